// Round 6
// baseline (1996.938 us; speedup 1.0000x reference)
//
#include <hip/hip_runtime.h>

typedef __bf16 bf16;
typedef __attribute__((ext_vector_type(8))) __bf16 bf16x8;
typedef __attribute__((ext_vector_type(4))) float f32x4;
typedef __attribute__((ext_vector_type(16))) float f32x16;
typedef __attribute__((ext_vector_type(4))) unsigned short u16x4;

__device__ __forceinline__ void gload_lds16(const void* g, void* l) {
  __builtin_amdgcn_global_load_lds(
      (const __attribute__((address_space(1))) void*)g,
      (__attribute__((address_space(3))) void*)l, 16, 0, 0);
}

__device__ __forceinline__ float sigmoidf_(float x) { return 1.0f / (1.0f + expf(-x)); }

__device__ __forceinline__ float bf2f(unsigned short u) {
  union { unsigned int i; float f; } v;
  v.i = ((unsigned int)u) << 16;
  return v.f;
}
__device__ __forceinline__ unsigned short f2bfbits(float x) {
  union { bf16 b; unsigned short u; } v;
  v.b = (bf16)x;
  return v.u;
}

#define SB() __builtin_amdgcn_sched_barrier(0)
#define BAR()                          \
  do {                                 \
    SB();                              \
    __builtin_amdgcn_s_barrier();      \
    SB();                              \
  } while (0)

#define MFMA16(a, b, c) __builtin_amdgcn_mfma_f32_16x16x32_bf16(a, b, c, 0, 0, 0)
#define MFMA32(a, b, c) __builtin_amdgcn_mfma_f32_32x32x16_bf16(a, b, c, 0, 0, 0)

// ---------------------------------------------------------------------------
// 256x256-tile GEMM, 32x32x16 MFMA, 2 phases/K-tile.
// A [M x K] bf16 (lda); Bw [4096 x K] bf16, P2-packed rows
//   (n' = q32*128 + gate*32 + jj32, source row = gate*1024 + q32*32 + jj32).
// Per-wave output 64x128 (WM=4 x WN=2): 2 row-tiles x 4 col-tiles (=4 gates).
// 3-bit XOR swizzle on LDS cols (conflict-free b128); staging source
// pre-unswizzled, linear gload_lds dest (rule #21).
// MODE 0: pack 4 gates -> u16x4 bf16 store, X layout (q32*128 + jj32*4 + g).
// MODE 1: fused LSTM cell; X (bf16) / bias (f32) in X layout;
//         c' = sig(f)*c + sig(i)*tanh(g); h = sig(o)*tanh(c') -> hout (ldh).
// ---------------------------------------------------------------------------
template<int MODE>
__global__ __launch_bounds__(512, 2)
void gemm32(const bf16* __restrict__ A, int lda,
            const bf16* __restrict__ Bw, int K,
            bf16* __restrict__ Cb,
            const bf16* __restrict__ X, const float* __restrict__ bias,
            float* __restrict__ cst, bf16* __restrict__ hout, int ldh) {
  extern __shared__ __align__(16) char smem_raw[];
  bf16* lsA = (bf16*)smem_raw;   // [2][256][64]
  bf16* lsB = lsA + 2 * 16384;   // [2][256][64]

  const int tid = threadIdx.x;
  const int lane = tid & 63;
  const int wave = tid >> 6;
  const int wm = wave >> 1;      // 0..3 (M)
  const int wn = wave & 1;       // 0..1 (N, 128 cols each)

  const int bid = blockIdx.x;
  const int wgid = (bid & 7) * 32 + (bid >> 3);  // XCD-bijective (256 wgs)
  const int m0 = (wgid >> 4) * 256, n0 = (wgid & 15) * 256;

  const int nkt = K >> 6;

  // staging: dest linear in tid; source col pre-unswizzled
  const int srow = tid >> 3;  // 0..63
  const int csw = ((tid & 7) ^ (srow & 7)) * 8;
  const bf16* gA = A + (size_t)m0 * lda + csw;
  const bf16* gB = Bw + (size_t)n0 * K + csw;

  auto stageA = [&](int kt) {
    bf16* d = lsA + (kt & 1) * 16384 + tid * 8;
    const bf16* s = gA + (size_t)srow * lda + (size_t)kt * 64;
    gload_lds16(s, d);
    gload_lds16(s + (size_t)64 * lda, d + 4096);
    gload_lds16(s + (size_t)128 * lda, d + 8192);
    gload_lds16(s + (size_t)192 * lda, d + 12288);
  };
  auto stageB = [&](int kt) {
    bf16* d = lsB + (kt & 1) * 16384 + tid * 8;
    const bf16* s = gB + (size_t)srow * K + (size_t)kt * 64;
    gload_lds16(s, d);
    gload_lds16(s + (size_t)64 * K, d + 4096);
    gload_lds16(s + (size_t)128 * K, d + 8192);
    gload_lds16(s + (size_t)192 * K, d + 12288);
  };

  // ds_read: element offset = row*64 + slot*8, slot = ((s<<1)|kh) ^ (lane&7)
  const int kh = lane >> 5;
  const int lx = lane & 7;
  const int co[4] = { (((0 << 1) | kh) ^ lx) * 8, (((1 << 1) | kh) ^ lx) * 8,
                      (((2 << 1) | kh) ^ lx) * 8, (((3 << 1) | kh) ^ lx) * 8 };
  const int abase = (wm * 64 + (lane & 31)) * 64;   // + r*2048
  const int bbase = (wn * 128 + (lane & 31)) * 64;  // + g*2048

  f32x16 acc[2][4] = {};

  // prologue
  stageA(0); stageB(0);
  asm volatile("s_waitcnt vmcnt(0)" ::: "memory");
  BAR();

  for (int u = 0; u < nkt; ++u) {
    const bf16* pA = lsA + (u & 1) * 16384;
    const bf16* pB = lsB + (u & 1) * 16384;
    bf16x8 av[2][2], bv[4][2];

    // ---- Ph0: read kslices 0,1; stage tile u+1; 16 MFMA ----
#pragma unroll
    for (int r = 0; r < 2; ++r)
#pragma unroll
      for (int s = 0; s < 2; ++s)
        av[r][s] = *(const bf16x8*)&pA[abase + r * 2048 + co[s]];
#pragma unroll
    for (int g = 0; g < 4; ++g)
#pragma unroll
      for (int s = 0; s < 2; ++s)
        bv[g][s] = *(const bf16x8*)&pB[bbase + g * 2048 + co[s]];
    if (u + 1 < nkt) { stageA(u + 1); stageB(u + 1); }
    BAR();
    __builtin_amdgcn_s_setprio(1);
#pragma unroll
    for (int s = 0; s < 2; ++s)
#pragma unroll
      for (int r = 0; r < 2; ++r)
#pragma unroll
        for (int g = 0; g < 4; ++g)
          acc[r][g] = MFMA32(av[r][s], bv[g][s], acc[r][g]);
    __builtin_amdgcn_s_setprio(0);
    BAR();

    // ---- Ph1: read kslices 2,3; 16 MFMA; drain staging before flip ----
#pragma unroll
    for (int r = 0; r < 2; ++r)
#pragma unroll
      for (int s = 0; s < 2; ++s)
        av[r][s] = *(const bf16x8*)&pA[abase + r * 2048 + co[s + 2]];
#pragma unroll
    for (int g = 0; g < 4; ++g)
#pragma unroll
      for (int s = 0; s < 2; ++s)
        bv[g][s] = *(const bf16x8*)&pB[bbase + g * 2048 + co[s + 2]];
    BAR();
    __builtin_amdgcn_s_setprio(1);
#pragma unroll
    for (int s = 0; s < 2; ++s)
#pragma unroll
      for (int r = 0; r < 2; ++r)
#pragma unroll
        for (int g = 0; g < 4; ++g)
          acc[r][g] = MFMA32(av[r][s], bv[g][s], acc[r][g]);
    __builtin_amdgcn_s_setprio(0);
    if (u + 1 < nkt) {
      SB();
      asm volatile("s_waitcnt vmcnt(0)" ::: "memory");
    }
    BAR();
  }

  // ---------------- epilogue ----------------
  // C layout (32x32): col = lane&31, row = (reg&3) + 8*(reg>>2) + 4*(lane>>5)
  const int jj32 = lane & 31;
  const int q32 = (n0 >> 7) + wn;             // wave-uniform q32 group
  const int xoff = q32 * 128 + jj32 * 4;
  const int rb = m0 + wm * 64 + ((lane >> 5) << 2);

  if constexpr (MODE == 0) {
#pragma unroll
    for (int r = 0; r < 2; ++r)
#pragma unroll
      for (int reg = 0; reg < 16; ++reg) {
        const int row = rb + r * 32 + (reg & 3) + 8 * (reg >> 2);
        u16x4 pk;
        pk[0] = f2bfbits(acc[r][0][reg]);
        pk[1] = f2bfbits(acc[r][1][reg]);
        pk[2] = f2bfbits(acc[r][2][reg]);
        pk[3] = f2bfbits(acc[r][3][reg]);
        *(u16x4*)&Cb[(size_t)row * 4096 + xoff] = pk;
      }
  } else {
    const int j = q32 * 32 + jj32;
    const f32x4 bq = *(const f32x4*)&bias[xoff];
#pragma unroll
    for (int r = 0; r < 2; ++r) {
#pragma unroll
      for (int reg = 0; reg < 16; ++reg) {
        const int row = rb + r * 32 + (reg & 3) + 8 * (reg >> 2);
        const u16x4 xv = *(const u16x4*)&X[(size_t)row * 4096 + xoff];
        const float gi = acc[r][0][reg] + bf2f(xv[0]) + bq[0];
        const float gf = acc[r][1][reg] + bf2f(xv[1]) + bq[1];
        const float gg = acc[r][2][reg] + bf2f(xv[2]) + bq[2];
        const float go = acc[r][3][reg] + bf2f(xv[3]) + bq[3];
        const size_t ci = (size_t)row * 1024 + j;
        const float cn = sigmoidf_(gf) * cst[ci] + sigmoidf_(gi) * tanhf(gg);
        cst[ci] = cn;
        hout[(size_t)row * ldh + j] = (bf16)(sigmoidf_(go) * tanhf(cn));
      }
    }
  }
}

// ---------------------------------------------------------------------------
// 2-phase GEMM for the out-projection (N=512).
// MODE 1: sigmoid + scatter to notes + bf16 note feedback.
// ---------------------------------------------------------------------------
template<int BM, int BN, int WM, int WN, int MODE>
__global__ __launch_bounds__(WM * WN * 64)
void gemm_bt(const bf16* __restrict__ A, int lda,
             const bf16* __restrict__ Bw, int ldb,
             float* __restrict__ C, int ldc, int K,
             const float* __restrict__ outb, float* __restrict__ dout,
             bf16* __restrict__ anote, int nstep) {
  constexpr int BK = 64;
  constexpr int THREADS = WM * WN * 64;
  constexpr int SM = BM / WM, SN = BN / WN;
  constexpr int FM = SM / 16, FN = SN / 16;

  __shared__ __align__(16) bf16 lsA[BM * BK];
  __shared__ __align__(16) bf16 lsB[BN * BK];

  const int tid = threadIdx.x;
  const int lane = tid & 63;
  const int wave = tid >> 6;
  const int wm = wave / WN, wn = wave % WN;
  const int m0 = blockIdx.y * BM;
  const int n0 = blockIdx.x * BN;

  f32x4 acc[FM][FN] = {};

  const bf16* gA = A + (size_t)m0 * lda;
  const bf16* gB = Bw + (size_t)n0 * ldb;

  for (int k0 = 0; k0 < K; k0 += BK) {
#pragma unroll
    for (int i = 0; i < (BM * 8) / THREADS; ++i) {
      int idx = i * THREADS + tid;
      gload_lds16(gA + (size_t)(idx >> 3) * lda + k0 + (idx & 7) * 8, &lsA[idx * 8]);
    }
#pragma unroll
    for (int i = 0; i < (BN * 8) / THREADS; ++i) {
      int idx = i * THREADS + tid;
      gload_lds16(gB + (size_t)(idx >> 3) * ldb + k0 + (idx & 7) * 8, &lsB[idx * 8]);
    }
    __syncthreads();

#pragma unroll
    for (int kk = 0; kk < BK; kk += 32) {
      bf16x8 av[FM], bv[FN];
#pragma unroll
      for (int i = 0; i < FM; ++i)
        av[i] = *(const bf16x8*)&lsA[(wm * SM + i * 16 + (lane & 15)) * BK + kk + (lane >> 4) * 8];
#pragma unroll
      for (int j = 0; j < FN; ++j)
        bv[j] = *(const bf16x8*)&lsB[(wn * SN + j * 16 + (lane & 15)) * BK + kk + (lane >> 4) * 8];
#pragma unroll
      for (int i = 0; i < FM; ++i)
#pragma unroll
        for (int j = 0; j < FN; ++j)
          acc[i][j] = MFMA16(av[i], bv[j], acc[i][j]);
    }
    __syncthreads();
  }

#pragma unroll
  for (int i = 0; i < FM; ++i) {
#pragma unroll
    for (int j = 0; j < FN; ++j) {
      const int col = n0 + wn * SN + j * 16 + (lane & 15);
      const int rbase = m0 + wm * SM + i * 16 + ((lane >> 4) << 2);
#pragma unroll
      for (int r = 0; r < 4; ++r) {
        const int row = rbase + r;
        float v = acc[i][j][r];
        if constexpr (MODE == 0) {
          C[(size_t)row * ldc + col] = v;
        } else {
          v = sigmoidf_(v + outb[col]);
          const int l = row >> 8, b = row & 255;
          dout[((size_t)(b * 256 + l * 16 + nstep)) * 512 + col] = v;
          anote[(size_t)row * 1536 + col] = (bf16)v;
        }
      }
    }
  }
}

// ---------------------------------------------------------------------------
// Conductor fused GEMM+cell, P2 layout. M=256 per level, K=1024, N=4096.
// Block: 32 rows x 256 cols (2 q32 groups); 4 waves (wm 0..1 x wj 0..1);
// per-wave N=128 = 8 x 16-col fragments t2 = gate*2 + jh.
// ---------------------------------------------------------------------------
__global__ __launch_bounds__(256)
void gemm_cell_c(const bf16* __restrict__ A,        // [256 x 1024] h_prev
                 const bf16* __restrict__ Bw,       // Wchh P2 [4096 x 1024]
                 const bf16* __restrict__ X,        // level slice, X layout
                 const float* __restrict__ bias,    // X layout
                 float* __restrict__ cst,           // cc [256 x 1024]
                 bf16* __restrict__ hout) {         // emb level [256 x 1024]
  __shared__ __align__(16) bf16 lsA[32 * 64];
  __shared__ __align__(16) bf16 lsB[256 * 64];

  const int tid = threadIdx.x;
  const int lane = tid & 63;
  const int wave = tid >> 6;
  const int wm = wave >> 1, wj = wave & 1;
  const int m0 = blockIdx.y * 32;
  const int nb = blockIdx.x;          // 0..15, cols nb*256..

  const int srow = tid >> 3;
  const int csw = ((tid & 7) ^ (srow & 7)) * 8;

  f32x4 acc[8] = {};

  // ds_read slot: ((kk>>3) + (lane>>4)) ^ (lane&7)
  const int lh = lane >> 4, lx = lane & 7;
  const int sl0 = ((0 + lh) ^ lx) * 8;
  const int sl1 = ((4 + lh) ^ lx) * 8;

  for (int kt = 0; kt < 16; ++kt) {
    // stage A (1 gload: 32x64) and B (8 gloads: 256x64), swizzled source
    {
      const int r = tid >> 3;  // 0..31
      gload_lds16(A + (size_t)(m0 + r) * 1024 + kt * 64 + csw, &lsA[tid * 8]);
#pragma unroll
      for (int h = 0; h < 8; ++h) {
        const int row = h * 32 + r;
        gload_lds16(Bw + (size_t)(nb * 256 + row) * 1024 + kt * 64 + csw,
                    &lsB[h * 2048 + tid * 8]);
      }
    }
    __syncthreads();

#pragma unroll
    for (int kk = 0; kk < 2; ++kk) {
      const int sl = kk ? sl1 : sl0;
      bf16x8 av = *(const bf16x8*)&lsA[(wm * 16 + (lane & 15)) * 64 + sl];
#pragma unroll
      for (int t2 = 0; t2 < 8; ++t2) {
        const int brow = wj * 128 + (t2 >> 1) * 32 + (t2 & 1) * 16 + (lane & 15);
        bf16x8 bv = *(const bf16x8*)&lsB[brow * 64 + sl];
        acc[t2] = MFMA16(av, bv, acc[t2]);
      }
    }
    __syncthreads();
  }

  // epilogue: all 4 gates of (row, j) live in this lane across t2 = gate*2+jh
  const int q32g = nb * 2 + wj;
  const int jj = lane & 15;
  const int rbase = m0 + wm * 16 + ((lane >> 4) << 2);
#pragma unroll
  for (int jh = 0; jh < 2; ++jh) {
    const int jj32 = jh * 16 + jj;
    const int j = q32g * 32 + jj32;
    const int xo = q32g * 128 + jj32 * 4;
    const f32x4 bq = *(const f32x4*)&bias[xo];
#pragma unroll
    for (int r = 0; r < 4; ++r) {
      const int row = rbase + r;
      const u16x4 xv = *(const u16x4*)&X[(size_t)row * 4096 + xo];
      const float gi = acc[0 + jh][r] + bf2f(xv[0]) + bq[0];
      const float gf = acc[2 + jh][r] + bf2f(xv[1]) + bq[1];
      const float gg = acc[4 + jh][r] + bf2f(xv[2]) + bq[2];
      const float go = acc[6 + jh][r] + bf2f(xv[3]) + bq[3];
      const size_t ci = (size_t)row * 1024 + j;
      const float c = sigmoidf_(gf) * cst[ci] + sigmoidf_(gi) * tanhf(gg);
      cst[ci] = c;
      hout[(size_t)row * 1024 + j] = (bf16)(sigmoidf_(go) * tanhf(c));
    }
  }
}

// ---------------- packing / init kernels ----------------

__global__ void conv_f32_bf16(const float* __restrict__ src, bf16* __restrict__ dst, int n) {
  int idx = blockIdx.x * 256 + threadIdx.x;
  if (idx < n) dst[idx] = (bf16)src[idx];
}

// P2 row: n' = q32*128 + gate*32 + jj32  ->  source row gate*1024 + q32*32 + jj32
__device__ __forceinline__ int p2_src_row(int n) {
  int q32 = n >> 7, gate = (n >> 5) & 3, jj = n & 31;
  return gate * 1024 + q32 * 32 + jj;
}

__global__ void pack_w_dec(const float* __restrict__ wih, const float* __restrict__ whh,
                           bf16* __restrict__ dst) {
  int idx = blockIdx.x * 256 + threadIdx.x;  // 4096*1536
  int n = idx / 1536, c = idx - n * 1536;
  int r = p2_src_row(n);
  float v = (c < 512) ? wih[(size_t)r * 1536 + 1024 + c] : whh[(size_t)r * 1024 + (c - 512)];
  dst[idx] = (bf16)v;
}

__global__ void pack_w_emb(const float* __restrict__ wih, bf16* __restrict__ dst) {
  int idx = blockIdx.x * 256 + threadIdx.x;  // 4096*1024
  int n = idx >> 10, c = idx & 1023;
  dst[idx] = (bf16)wih[(size_t)p2_src_row(n) * 1536 + c];
}

__global__ void pack_w_p2(const float* __restrict__ src, bf16* __restrict__ dst, int Kw) {
  int idx = blockIdx.x * 256 + threadIdx.x;  // 4096*Kw
  int n = idx / Kw, c = idx - n * Kw;
  dst[idx] = (bf16)src[(size_t)p2_src_row(n) * Kw + c];
}

// X-layout bias: dst[q32*128 + jj32*4 + g] = bih[r] + bhh[r]
__global__ void pack_bias(const float* __restrict__ bih, const float* __restrict__ bhh,
                          float* __restrict__ dst) {
  int n = blockIdx.x * 256 + threadIdx.x;  // 4096
  int q32 = n >> 7, jj = (n >> 2) & 31, g = n & 3;
  int r = g * 1024 + q32 * 32 + jj;
  dst[n] = bih[r] + bhh[r];
}

__global__ void pack_zb(const float* __restrict__ z, bf16* __restrict__ dst) {
  int idx = blockIdx.x * 256 + threadIdx.x;  // 4096*512
  int m = idx >> 9, k = idx & 511;
  int l = m >> 8, b = m & 255;
  dst[idx] = (bf16)z[((size_t)b * 256 + 16 * l) * 512 + k];
}

__global__ void init_cond(float* __restrict__ cc, bf16* __restrict__ hz0) {
  int idx = blockIdx.x * 256 + threadIdx.x;  // 256*1024
  cc[idx] = 0.f;
  hz0[idx] = (bf16)0.f;
}

__global__ void init_state(const float* __restrict__ h0, const float* __restrict__ c0,
                           bf16* __restrict__ Abuf, float* __restrict__ cdec) {
  int idx = blockIdx.x * 256 + threadIdx.x;  // 4096*1536
  int m = idx / 1536, c = idx - m * 1536;
  if (c < 512) {
    Abuf[idx] = (bf16)0.f;
  } else {
    int j = c - 512;
    size_t s = (size_t)m * 1024 + j;
    Abuf[idx] = (bf16)h0[s];
    cdec[s] = c0[s];
  }
}

extern "C" void kernel_launch(void* const* d_in, const int* in_sizes, int n_in,
                              void* d_out, int out_size, void* d_ws, size_t ws_size,
                              hipStream_t stream) {
  const float* z        = (const float*)d_in[0];
  const float* dec_h0   = (const float*)d_in[1];
  const float* dec_c0   = (const float*)d_in[2];
  const float* cond_Wih = (const float*)d_in[5];
  const float* cond_Whh = (const float*)d_in[6];
  const float* cond_bih = (const float*)d_in[7];
  const float* cond_bhh = (const float*)d_in[8];
  const float* dec_Wih  = (const float*)d_in[9];
  const float* dec_Whh  = (const float*)d_in[10];
  const float* dec_bih  = (const float*)d_in[11];
  const float* dec_bhh  = (const float*)d_in[12];
  const float* out_W    = (const float*)d_in[13];
  const float* out_b    = (const float*)d_in[14];
  float* out = (float*)d_out;

  char* ws = (char*)d_ws;
  size_t off = 0;
  auto alloc = [&](size_t bytes) {
    void* p = ws + off;
    off += (bytes + 255) & ~(size_t)255;
    return p;
  };
  bf16* E     = (bf16*)alloc(4096ull * 4096 * 2);   // emb @ We^T, X layout
  bf16* Xz    = (bf16*)alloc(4096ull * 4096 * 2);   // z @ Wcih^T, X layout
  float* cdec = (float*)alloc(4096ull * 1024 * 4);
  bf16* Ab0   = (bf16*)alloc(4096ull * 1536 * 2);   // state ping [note | h]
  bf16* Ab1   = (bf16*)alloc(4096ull * 1536 * 2);   // state pong
  bf16* Wd    = (bf16*)alloc(4096ull * 1536 * 2);   // P2 [Wih_note | Whh]
  bf16* We    = (bf16*)alloc(4096ull * 1024 * 2);   // P2 Wih_emb
  bf16* Wcih  = (bf16*)alloc(4096ull * 512 * 2);    // P2
  bf16* Wchh  = (bf16*)alloc(4096ull * 1024 * 2);   // P2
  bf16* Wo    = (bf16*)alloc(512ull * 1024 * 2);
  float* cc   = (float*)alloc(256ull * 1024 * 4);
  bf16* emb   = (bf16*)alloc(4096ull * 1024 * 2);
  bf16* Zb    = (bf16*)alloc(4096ull * 512 * 2);
  bf16* hz0   = (bf16*)alloc(256ull * 1024 * 2);
  float* bdP  = (float*)alloc(4096ull * 4);
  float* bcP  = (float*)alloc(4096ull * 4);

  dim3 b256(256);

  hipFuncSetAttribute(reinterpret_cast<const void*>(&gemm32<0>),
                      hipFuncAttributeMaxDynamicSharedMemorySize, 131072);
  hipFuncSetAttribute(reinterpret_cast<const void*>(&gemm32<1>),
                      hipFuncAttributeMaxDynamicSharedMemorySize, 131072);

  // packing
  pack_w_p2<<<4096 * 512 / 256, b256, 0, stream>>>(cond_Wih, Wcih, 512);
  pack_w_p2<<<4096 * 1024 / 256, b256, 0, stream>>>(cond_Whh, Wchh, 1024);
  conv_f32_bf16<<<(512 * 1024 + 255) / 256, b256, 0, stream>>>(out_W, Wo, 512 * 1024);
  pack_w_dec<<<4096 * 1536 / 256, b256, 0, stream>>>(dec_Wih, dec_Whh, Wd);
  pack_w_emb<<<4096 * 1024 / 256, b256, 0, stream>>>(dec_Wih, We);
  pack_bias<<<16, b256, 0, stream>>>(dec_bih, dec_bhh, bdP);
  pack_bias<<<16, b256, 0, stream>>>(cond_bih, cond_bhh, bcP);
  pack_zb<<<4096 * 512 / 256, b256, 0, stream>>>(z, Zb);
  init_cond<<<256 * 1024 / 256, b256, 0, stream>>>(cc, hz0);
  init_state<<<4096 * 1536 / 256, b256, 0, stream>>>(dec_h0, dec_c0, Ab0, cdec);

  // Xz = Zb @ Wcih^T (X layout)
  gemm32<0><<<256, 512, 131072, stream>>>(Zb, 512, Wcih, 512, Xz,
                                          nullptr, nullptr, nullptr, nullptr, 0);

  // conductor chain: 16 sequential fused steps (M=256)
  for (int l = 0; l < 16; ++l) {
    const bf16* hprev = (l == 0) ? hz0 : (emb + (size_t)(l - 1) * 256 * 1024);
    gemm_cell_c<<<dim3(16, 8), b256, 0, stream>>>(
        hprev, Wchh, Xz + (size_t)l * 256 * 4096, bcP, cc,
        emb + (size_t)l * 256 * 1024);
  }

  // E = emb @ We^T (X layout)
  gemm32<0><<<256, 512, 131072, stream>>>(emb, 1024, We, 1024, E,
                                          nullptr, nullptr, nullptr, nullptr, 0);

  // 16 autoregressive decoder steps (M = 4096), ping-pong state (race-free)
  for (int n = 0; n < 16; ++n) {
    bf16* Sc = (n & 1) ? Ab1 : Ab0;
    bf16* Sn = (n & 1) ? Ab0 : Ab1;
    gemm32<1><<<256, 512, 131072, stream>>>(Sc, 1536, Wd, 1536, nullptr,
                                            E, bdP, cdec, Sn + 512, 1536);
    gemm_bt<128, 64, 2, 2, 1><<<dim3(512 / 64, 4096 / 128), dim3(256), 0, stream>>>(
        Sn + 512, 1536, Wo, 1024, nullptr, 0, 1024, out_b, out, Sn, n);
  }
}